// Round 3
// baseline (42424.402 us; speedup 1.0000x reference)
//
#include <hip/hip_runtime.h>
#include <math.h>

// ---------------------------------------------------------------------------
// Generator_429496729630 — round 2: all-float32 (inputs/outputs are f32; the
// harness only bf16-rounds for COMPARISON). Row-slot layout in d_out:
// d_out = 16384 rows x 3072 f32 (12288 B). Per-row slots (element offsets):
//   G  [0,2048)     : gate preactivations for the current layer
//   hA [2048,2560)  : hidden ping (combine out; layers 1,3 out; heads in)
//   hB [2560,3072)  : hidden pong (layers 0,2 out)
// All kernels are row-local in their read/write sets within one launch.
// ws usage: cstate only (512 KB f32), never read before written (t==0 guard).
// ---------------------------------------------------------------------------

#define B_    256
#define T_    64
#define EMB_  128
#define HID_  512
#define G4_   2048
#define CIN_  704
#define HA_   576
#define ROW_  3072
#define OFF_HA 2048
#define OFF_HB 2560

struct Params {
  const float* label; const int* length; const int* x; const int* xnow;
  const float* emb[5]; const float* pad;
  const float* condW[4]; const float* condB[4];
  const float* lenW; const float* lenB;
  const float* combW; const float* combB;
  const float* Wih; const float* Whh; const float* bih; const float* bhh;
  const float* outW[5]; const float* outB[5];
  float* cstate;
  float* out;
};

// ---------------- label-routed combine FC (+ length branch, label argmax) ----
__global__ __launch_bounds__(256) void k_combine(Params P) {
  __shared__ float sA[16][CIN_];   // 45KB
  __shared__ float sLen[64];
  int b = blockIdx.x >> 2, t0 = (blockIdx.x & 3) * 16;
  int tid = threadIdx.x;
  int li = P.length[b] - 1;
  if (tid < 64) {
    float v = P.lenW[tid * 64 + li] + P.lenB[tid];
    sLen[tid] = v > 0.f ? v : 0.f;
  }
  float best = P.label[b * 8]; int l = 0;
  #pragma unroll
  for (int k = 1; k < 8; ++k) {
    float lv = P.label[b * 8 + k];
    if (lv > best) { best = lv; l = k; }   // strict > : first max (np.argmax)
  }
  __syncthreads();
  for (int tt = 0; tt < 16; ++tt) {
    int t = t0 + tt;
    for (int k = tid; k < CIN_; k += 256) {
      float v;
      if (k < 640) {
        int a = k >> 7, e = k & 127;
        int xi = P.x[((b * T_ + t) * 5) + a];
        v = P.emb[a][xi * EMB_ + e];
      } else {
        v = sLen[k - 640];
      }
      sA[tt][k] = v;
    }
  }
  __syncthreads();
  int hg = tid & 127, mh = tid >> 7;
  int h = hg * 4, tb = mh * 8;
  const float* W0 = P.combW + ((size_t)(l * HID_ + h)) * CIN_;
  float acc[4][8];
  #pragma unroll
  for (int c = 0; c < 4; ++c)
    #pragma unroll
    for (int m = 0; m < 8; ++m) acc[c][m] = 0.f;
  for (int k = 0; k < CIN_; k += 4) {
    float4 w0 = *(const float4*)(const void*)(W0 + k);
    float4 w1 = *(const float4*)(const void*)(W0 + CIN_ + k);
    float4 w2 = *(const float4*)(const void*)(W0 + 2 * CIN_ + k);
    float4 w3 = *(const float4*)(const void*)(W0 + 3 * CIN_ + k);
    #pragma unroll
    for (int m = 0; m < 8; ++m) {
      float4 av = *(const float4*)&sA[tb + m][k];
      acc[0][m] += w0.x*av.x + w0.y*av.y + w0.z*av.z + w0.w*av.w;
      acc[1][m] += w1.x*av.x + w1.y*av.y + w1.z*av.z + w1.w*av.w;
      acc[2][m] += w2.x*av.x + w2.y*av.y + w2.z*av.z + w2.w*av.w;
      acc[3][m] += w3.x*av.x + w3.y*av.y + w3.z*av.z + w3.w*av.w;
    }
  }
  #pragma unroll
  for (int c = 0; c < 4; ++c) {
    float bias = P.combB[l * HID_ + h + c];
    #pragma unroll
    for (int m = 0; m < 8; ++m) {
      float v = acc[c][m] + bias;
      P.out[((size_t)(b * T_ + t0 + tb + m)) * ROW_ + OFF_HA + h + c] = v > 0.f ? v : 0.f;
    }
  }
}

// ---------------- bulk gates: G(m) = x(m)@Wih^T + bih + bhh (row-local) -----
__global__ __launch_bounds__(256) void k_bulkG(Params P, int layer, int in_off) {
  __shared__ float sA[16][512];   // 32KB
  int mt = blockIdx.x >> 2, rt = blockIdx.x & 3;
  int m0 = mt * 16, r0 = rt * 512;
  int tid = threadIdx.x;
  for (int i = tid; i < 16 * 512; i += 256) {
    int tt = i >> 9, k = i & 511;
    sA[tt][k] = P.out[((size_t)(m0 + tt)) * ROW_ + in_off + k];
  }
  __syncthreads();
  const float* W = P.Wih + (size_t)layer * G4_ * HID_;
  int rg = tid & 127, mh = tid >> 7;
  int r = r0 + rg * 4, tb = mh * 8;
  const float* Wr = W + (size_t)r * HID_;
  float acc[4][8];
  #pragma unroll
  for (int c = 0; c < 4; ++c)
    #pragma unroll
    for (int m = 0; m < 8; ++m) acc[c][m] = 0.f;
  for (int k = 0; k < 512; k += 4) {
    float4 w0 = *(const float4*)(const void*)(Wr + k);
    float4 w1 = *(const float4*)(const void*)(Wr + 512 + k);
    float4 w2 = *(const float4*)(const void*)(Wr + 1024 + k);
    float4 w3 = *(const float4*)(const void*)(Wr + 1536 + k);
    #pragma unroll
    for (int m = 0; m < 8; ++m) {
      float4 av = *(const float4*)&sA[tb + m][k];
      acc[0][m] += w0.x*av.x + w0.y*av.y + w0.z*av.z + w0.w*av.w;
      acc[1][m] += w1.x*av.x + w1.y*av.y + w1.z*av.z + w1.w*av.w;
      acc[2][m] += w2.x*av.x + w2.y*av.y + w2.z*av.z + w2.w*av.w;
      acc[3][m] += w3.x*av.x + w3.y*av.y + w3.z*av.z + w3.w*av.w;
    }
  }
  #pragma unroll
  for (int c = 0; c < 4; ++c) {
    float bias = P.bih[layer * G4_ + r + c] + P.bhh[layer * G4_ + r + c];
    #pragma unroll
    for (int m = 0; m < 8; ++m)
      P.out[((size_t)(m0 + tb + m)) * ROW_ + r + c] = acc[c][m] + bias;
  }
}

// ---------------- one LSTM timestep ----------------
// grid 1024 = 16 s-tiles (16 samples) x 64 j-tiles (8 hidden units)
__global__ __launch_bounds__(256) void k_step(Params P, int layer, int t, int out_off) {
  __shared__ __align__(16) float sHs[16 * 516];  // pad 512->516 (bank shift 4)
  __shared__ float sGt[16][33];
  int s0 = (blockIdx.x & 15) * 16, j0 = (blockIdx.x >> 4) * 8;
  int tid = threadIdx.x;
  if (t == 0) {
    for (int i = tid; i < 16 * 512; i += 256) {
      int s = i >> 9, k = i & 511;
      sHs[s * 516 + k] = 0.f;
    }
  } else {
    for (int i = tid; i < 16 * 512; i += 256) {
      int s = i >> 9, k = i & 511;
      sHs[s * 516 + k] = P.out[((size_t)(s0 + s) * T_ + (t - 1)) * ROW_ + out_off + k];
    }
  }
  __syncthreads();
  const float* W = P.Whh + (size_t)layer * G4_ * HID_;
  int s = tid >> 4, rg = tid & 15;
  int rl0 = rg * 2, rl1 = rl0 + 1;
  int g0 = rl0 >> 3, jj0 = rl0 & 7;
  int g1 = rl1 >> 3, jj1 = rl1 & 7;
  const float4* w0p = (const float4*)(const void*)(W + (size_t)(g0 * HID_ + j0 + jj0) * HID_);
  const float4* w1p = (const float4*)(const void*)(W + (size_t)(g1 * HID_ + j0 + jj1) * HID_);
  const float4* hp  = (const float4*)(const void*)(sHs + s * 516);
  float acc0 = 0.f, acc1 = 0.f;
  for (int kc = 0; kc < 128; ++kc) {
    float4 h = hp[kc];
    float4 w0 = w0p[kc], w1 = w1p[kc];
    acc0 += h.x*w0.x + h.y*w0.y + h.z*w0.z + h.w*w0.w;
    acc1 += h.x*w1.x + h.y*w1.y + h.z*w1.z + h.w*w1.w;
  }
  sGt[s][rl0] = acc0;
  sGt[s][rl1] = acc1;
  __syncthreads();
  if (tid < 128) {
    int sl = tid >> 3, jj = tid & 7;
    int b = s0 + sl, j = j0 + jj;
    size_t mbase = ((size_t)b * T_ + t) * ROW_;
    float zi = P.out[mbase + 0 * HID_ + j] + sGt[sl][0 * 8 + jj];
    float zf = P.out[mbase + 1 * HID_ + j] + sGt[sl][1 * 8 + jj];
    float zg = P.out[mbase + 2 * HID_ + j] + sGt[sl][2 * 8 + jj];
    float zo = P.out[mbase + 3 * HID_ + j] + sGt[sl][3 * 8 + jj];
    float cp = (t == 0) ? 0.f : P.cstate[(size_t)b * HID_ + j];
    float si = 1.f / (1.f + expf(-zi));
    float sf = 1.f / (1.f + expf(-zf));
    float so = 1.f / (1.f + expf(-zo));
    float cn = sf * cp + si * tanhf(zg);
    P.cstate[(size_t)b * HID_ + j] = cn;
    P.out[mbase + out_off + j] = so * tanhf(cn);
  }
}

// ---------------- heads (attr fused) -> logits overwrite own rows ----------
// grid 2048 = 8 rows per block
__global__ __launch_bounds__(256) void k_heads(Params P) {
  __shared__ float sN[8][512];      // now_emb 16KB
  __shared__ float sH[8][512];      // hidden  16KB
  __shared__ float sAt[8][5][64];   // attrs   10KB
  int m0 = blockIdx.x * 8;
  int tid = threadIdx.x;
  for (int i = tid; i < 8 * 512; i += 256) {
    int tt = i >> 9, k = i & 511;
    int a = k >> 7, e = k & 127;
    int xi = P.xnow[((m0 + tt) * 5) + a];
    sN[tt][k] = P.emb[a][xi * EMB_ + e];
    sH[tt][k] = P.out[((size_t)(m0 + tt)) * ROW_ + OFF_HA + k];
  }
  for (int i = tid; i < 8 * 64; i += 256) {
    int tt = i >> 6, j = i & 63;
    sAt[tt][0][j] = P.pad[j];
  }
  __syncthreads();
  // fused cond MLPs: one wave per head (uniform trip count)
  {
    int ih = tid >> 6, j = tid & 63;
    int Klen = (ih + 1) * EMB_;
    const float* Wr = P.condW[ih] + (size_t)j * Klen;
    float acc[8] = {0.f,0.f,0.f,0.f,0.f,0.f,0.f,0.f};
    for (int k = 0; k < Klen; k += 4) {
      float4 w = *(const float4*)(const void*)(Wr + k);
      #pragma unroll
      for (int m = 0; m < 8; ++m) {
        float4 av = *(const float4*)&sN[m][k];
        acc[m] += w.x*av.x + w.y*av.y + w.z*av.z + w.w*av.w;
      }
    }
    float bias = P.condB[ih][j];
    #pragma unroll
    for (int m = 0; m < 8; ++m) {
      float v = acc[m] + bias;
      sAt[m][ih + 1][j] = v > 0.f ? v : 0.f;
    }
  }
  __syncthreads();
  const int V[5] = {256, 256, 1024, 1024, 512};
  int off = 0;
  int cg = tid & 127, mh = tid >> 7, tb = mh * 4;
  for (int head = 0; head < 5; ++head) {
    const float* W = P.outW[head];
    const float* bias = P.outB[head];
    int Vh = V[head];
    for (int c0 = cg * 4; c0 < Vh; c0 += 512) {
      const float* Wr = W + (size_t)c0 * HA_;
      float acc[4][4];
      #pragma unroll
      for (int c = 0; c < 4; ++c)
        #pragma unroll
        for (int m = 0; m < 4; ++m) acc[c][m] = 0.f;
      for (int k = 0; k < 512; k += 4) {
        float4 w0 = *(const float4*)(const void*)(Wr + k);
        float4 w1 = *(const float4*)(const void*)(Wr + HA_ + k);
        float4 w2 = *(const float4*)(const void*)(Wr + 2 * HA_ + k);
        float4 w3 = *(const float4*)(const void*)(Wr + 3 * HA_ + k);
        #pragma unroll
        for (int m = 0; m < 4; ++m) {
          float4 av = *(const float4*)&sH[tb + m][k];
          acc[0][m] += w0.x*av.x + w0.y*av.y + w0.z*av.z + w0.w*av.w;
          acc[1][m] += w1.x*av.x + w1.y*av.y + w1.z*av.z + w1.w*av.w;
          acc[2][m] += w2.x*av.x + w2.y*av.y + w2.z*av.z + w2.w*av.w;
          acc[3][m] += w3.x*av.x + w3.y*av.y + w3.z*av.z + w3.w*av.w;
        }
      }
      for (int k = 0; k < 64; k += 4) {
        float4 w0 = *(const float4*)(const void*)(Wr + 512 + k);
        float4 w1 = *(const float4*)(const void*)(Wr + HA_ + 512 + k);
        float4 w2 = *(const float4*)(const void*)(Wr + 2 * HA_ + 512 + k);
        float4 w3 = *(const float4*)(const void*)(Wr + 3 * HA_ + 512 + k);
        #pragma unroll
        for (int m = 0; m < 4; ++m) {
          float4 av = *(const float4*)&sAt[tb + m][head][k];
          acc[0][m] += w0.x*av.x + w0.y*av.y + w0.z*av.z + w0.w*av.w;
          acc[1][m] += w1.x*av.x + w1.y*av.y + w1.z*av.z + w1.w*av.w;
          acc[2][m] += w2.x*av.x + w2.y*av.y + w2.z*av.z + w2.w*av.w;
          acc[3][m] += w3.x*av.x + w3.y*av.y + w3.z*av.z + w3.w*av.w;
        }
      }
      #pragma unroll
      for (int c = 0; c < 4; ++c) {
        float bi = bias[c0 + c];
        #pragma unroll
        for (int m = 0; m < 4; ++m)
          P.out[((size_t)(m0 + tb + m)) * ROW_ + off + c0 + c] = acc[c][m] + bi;
      }
    }
    off += Vh;
  }
}

// ---------------- in-place log_softmax over each head's slice ----------------
__global__ __launch_bounds__(256) void k_lsm(Params P) {
  __shared__ float sred[4];
  int m = blockIdx.x;
  float* row0 = P.out + (size_t)m * ROW_;
  int tid = threadIdx.x, lane = tid & 63, wid = tid >> 6;
  const int V[5] = {256, 256, 1024, 1024, 512};
  int off = 0;
  for (int head = 0; head < 5; ++head) {
    float* row = row0 + off; int Vh = V[head];
    float mx = -1e30f;
    for (int c = tid; c < Vh; c += 256) mx = fmaxf(mx, row[c]);
    for (int o = 32; o > 0; o >>= 1) mx = fmaxf(mx, __shfl_down(mx, o, 64));
    if (lane == 0) sred[wid] = mx;
    __syncthreads();
    mx = fmaxf(fmaxf(sred[0], sred[1]), fmaxf(sred[2], sred[3]));
    __syncthreads();
    float s = 0.f;
    for (int c = tid; c < Vh; c += 256) s += expf(row[c] - mx);
    for (int o = 32; o > 0; o >>= 1) s += __shfl_down(s, o, 64);
    if (lane == 0) sred[wid] = s;
    __syncthreads();
    float lse = mx + logf(sred[0] + sred[1] + sred[2] + sred[3]);
    __syncthreads();
    for (int c = tid; c < Vh; c += 256) row[c] = row[c] - lse;
    off += Vh;
  }
}

extern "C" void kernel_launch(void* const* d_in, const int* in_sizes, int n_in,
                              void* d_out, int out_size, void* d_ws, size_t ws_size,
                              hipStream_t stream) {
  (void)in_sizes; (void)n_in; (void)out_size; (void)ws_size;
  Params P;
  P.label  = (const float*)d_in[0];
  P.length = (const int*)  d_in[1];
  P.x      = (const int*)  d_in[2];
  P.xnow   = (const int*)  d_in[3];
  for (int i = 0; i < 5; ++i) P.emb[i] = (const float*)d_in[4 + i];
  P.pad = (const float*)d_in[9];
  for (int i = 0; i < 4; ++i) {
    P.condW[i] = (const float*)d_in[10 + 2 * i];
    P.condB[i] = (const float*)d_in[11 + 2 * i];
  }
  P.lenW  = (const float*)d_in[18]; P.lenB  = (const float*)d_in[19];
  P.combW = (const float*)d_in[20]; P.combB = (const float*)d_in[21];
  P.Wih   = (const float*)d_in[22]; P.Whh   = (const float*)d_in[23];
  P.bih   = (const float*)d_in[24]; P.bhh   = (const float*)d_in[25];
  for (int i = 0; i < 5; ++i) {
    P.outW[i] = (const float*)d_in[26 + 2 * i];
    P.outB[i] = (const float*)d_in[27 + 2 * i];
  }
  P.cstate = (float*)d_ws;   // 512 KB, guarded by t==0 (never read pre-write)
  P.out = (float*)d_out;

  k_combine<<<1024, 256, 0, stream>>>(P);
  for (int l = 0; l < 4; ++l) {
    int in_off  = (l & 1) ? OFF_HB : OFF_HA;   // l0:hA l1:hB l2:hA l3:hB
    int out_off = (l & 1) ? OFF_HA : OFF_HB;   // final hidden lands in hA
    k_bulkG<<<4096, 256, 0, stream>>>(P, l, in_off);
    for (int t = 0; t < T_; ++t)
      k_step<<<1024, 256, 0, stream>>>(P, l, t, out_off);
  }
  k_heads<<<2048,  256, 0, stream>>>(P);
  k_lsm  <<<16384, 256, 0, stream>>>(P);
}

// Round 4
// 32933.566 us; speedup vs baseline: 1.2882x; 1.2882x over previous
//
#include <hip/hip_runtime.h>
#include <math.h>

// ---------------------------------------------------------------------------
// Generator_429496729630 — round 3: persistent cooperative LSTM kernel.
//
// d_out = 16384 rows x 3072 f32. Per-row slots (element offsets):
//   G  [0,2048)     : gate preactivations for the current layer
//   hA [2048,2560)  : hidden ping (combine out; layers 1,3 out; heads in)
//   hB [2560,3072)  : hidden pong (layers 0,2 out)
// Inside k_lstm, per layer (in=in_off slot, out=out_off slot):
//   T1: Wih^T (k-major, flat j = (r>>8)*131072 + k*256 + (r&255))
//       -> stored in OUT slot rows 0..8191 (dead until phase B writes h)
//   A : G = h_in @ Wih^T + bih + bhh     (reads IN slot + Wt_ih, writes G)
//   T2: Whh^T (ut-blocked, flat j = ut*65536 + k*128 + ulocal*4 + gate)
//       -> stored in IN slot rows 0..8191 (dead after phase A)
//   B : 64 recurrent steps; 256 blocks = 16 sample-groups x 16 unit-tiles;
//       c-state in registers; 16-block atomic group barrier per step.
// ws: 256 B of barrier counters only (memset each launch).
// ---------------------------------------------------------------------------

#define B_    256
#define T_    64
#define EMB_  128
#define HID_  512
#define G4_   2048
#define CIN_  704
#define HA_   576
#define ROW_  3072
#define OFF_HA 2048
#define OFF_HB 2560

struct Params {
  const float* label; const int* length; const int* x; const int* xnow;
  const float* emb[5]; const float* pad;
  const float* condW[4]; const float* condB[4];
  const float* lenW; const float* lenB;
  const float* combW; const float* combB;
  const float* Wih; const float* Whh; const float* bih; const float* bhh;
  const float* outW[5]; const float* outB[5];
  unsigned int* bar;
  float* out;
};

// generation-based multi-block barrier (device-scope atomics, agent scope)
__device__ __forceinline__ void multi_barrier(unsigned int* cnt, unsigned int* gen,
                                              unsigned int n) {
  __syncthreads();
  if (threadIdx.x == 0) {
    __threadfence();
    unsigned int g = __hip_atomic_load(gen, __ATOMIC_RELAXED, __HIP_MEMORY_SCOPE_AGENT);
    unsigned int a = __hip_atomic_fetch_add(cnt, 1u, __ATOMIC_ACQ_REL, __HIP_MEMORY_SCOPE_AGENT);
    if (a == n - 1u) {
      __hip_atomic_store(cnt, 0u, __ATOMIC_RELAXED, __HIP_MEMORY_SCOPE_AGENT);
      __hip_atomic_store(gen, g + 1u, __ATOMIC_RELEASE, __HIP_MEMORY_SCOPE_AGENT);
    } else {
      while (__hip_atomic_load(gen, __ATOMIC_ACQUIRE, __HIP_MEMORY_SCOPE_AGENT) == g) {
        __builtin_amdgcn_s_sleep(2);
      }
    }
    __threadfence();
  }
  __syncthreads();
}

// ---------------- persistent cooperative LSTM ----------------
__global__ __launch_bounds__(256, 1) void k_lstm(Params P) {
  __shared__ float smem[10304];   // 41216 B: max(transpose 4608, B: 8256+2048)
  unsigned int* bar = P.bar;
  const int tid = threadIdx.x;
  const int blk = blockIdx.x;
  const int ut = blk & 15, sg = blk >> 4;             // phase-B roles
  const int ug = tid & 7, sl = (tid >> 3) & 15, kh = tid >> 7;

  for (int l = 0; l < 4; ++l) {
    const int in_off  = (l & 1) ? OFF_HB : OFF_HA;
    const int out_off = (l & 1) ? OFF_HA : OFF_HB;
    const float* Wih = P.Wih + (size_t)l * G4_ * HID_;
    const float* Whh = P.Whh + (size_t)l * G4_ * HID_;

    // ---- T1: transpose Wih -> Wt_ih (k-major) into OUT slot rows 0..8191 ----
    {
      const int rt = blk >> 4, kt = blk & 15;
      const int r0 = rt * 128, k0 = kt * 32;
      const int ul = tid >> 3, kl = (tid & 7) * 4;
      #pragma unroll
      for (int p = 0; p < 4; ++p) {
        float4 v = *(const float4*)(Wih + (size_t)(r0 + p * 32 + ul) * HID_ + k0 + kl);
        *(float4*)&smem[(p * 32 + ul) * 36 + kl] = v;
      }
      __syncthreads();
      const int kk = tid >> 3, qb = (tid & 7) * 4;
      #pragma unroll
      for (int p = 0; p < 4; ++p) {
        int rl = qb + p * 32;
        float4 v = make_float4(smem[(rl + 0) * 36 + kk], smem[(rl + 1) * 36 + kk],
                               smem[(rl + 2) * 36 + kk], smem[(rl + 3) * 36 + kk]);
        int kabs = k0 + kk;
        int row = (r0 >> 8) * 256 + (kabs >> 1);
        int col = out_off + (kabs & 1) * 256 + (r0 & 255) + rl;
        *(float4*)&P.out[(size_t)row * ROW_ + col] = v;
      }
    }
    multi_barrier(&bar[0], &bar[1], 256);

    // ---- A: G = h_in @ Wih^T + bih + bhh (no LDS; coalesced Wt, bcast A) ----
    {
      const int rg = tid & 63, mh = tid >> 6;
      const int m_base = blk * 64;
      for (int sub = 0; sub < 2; ++sub) {
        const float* arow[8];
        #pragma unroll
        for (int mm = 0; mm < 8; ++mm)
          arow[mm] = P.out + (size_t)(m_base + sub * 32 + mh * 8 + mm) * ROW_ + in_off;
        for (int p = 0; p < 8; ++p) {
          float acc[4][8];
          #pragma unroll
          for (int c = 0; c < 4; ++c)
            #pragma unroll
            for (int m = 0; m < 8; ++m) acc[c][m] = 0.f;
          const float* wp = P.out + (size_t)(p * 256) * ROW_ + out_off + rg * 4;
          for (int kq = 0; kq < 64; ++kq) {
            float4 w0 = *(const float4*)(wp);              // k=4kq
            float4 w1 = *(const float4*)(wp + 256);        // k=4kq+1
            float4 w2 = *(const float4*)(wp + ROW_);       // k=4kq+2
            float4 w3 = *(const float4*)(wp + ROW_ + 256); // k=4kq+3
            #pragma unroll
            for (int mm = 0; mm < 8; ++mm) {
              float4 a = *(const float4*)(arow[mm] + kq * 4);
              acc[0][mm] += w0.x * a.x + w1.x * a.y + w2.x * a.z + w3.x * a.w;
              acc[1][mm] += w0.y * a.x + w1.y * a.y + w2.y * a.z + w3.y * a.w;
              acc[2][mm] += w0.z * a.x + w1.z * a.y + w2.z * a.z + w3.z * a.w;
              acc[3][mm] += w0.w * a.x + w1.w * a.y + w2.w * a.z + w3.w * a.w;
            }
            wp += 2 * ROW_;
          }
          int r4 = p * 256 + rg * 4;
          float4 bi = *(const float4*)(P.bih + l * G4_ + r4);
          float4 bh = *(const float4*)(P.bhh + l * G4_ + r4);
          float bx = bi.x + bh.x, by = bi.y + bh.y, bz = bi.z + bh.z, bw = bi.w + bh.w;
          #pragma unroll
          for (int mm = 0; mm < 8; ++mm) {
            int m = m_base + sub * 32 + mh * 8 + mm;
            *(float4*)&P.out[(size_t)m * ROW_ + r4] =
              make_float4(acc[0][mm] + bx, acc[1][mm] + by,
                          acc[2][mm] + bz, acc[3][mm] + bw);
          }
        }
      }
    }
    multi_barrier(&bar[0], &bar[1], 256);

    // ---- T2: transpose Whh -> Wt_hh (ut-blocked) into IN slot rows 0..8191 ----
    {
      const int utt = blk >> 4, kt = blk & 15;
      const int k0 = kt * 32;
      const int ul = tid >> 3, kl = (tid & 7) * 4;
      #pragma unroll
      for (int g = 0; g < 4; ++g) {
        float4 v = *(const float4*)(Whh + (size_t)(g * 512 + utt * 32 + ul) * HID_ + k0 + kl);
        *(float4*)&smem[(ul * 4 + g) * 36 + kl] = v;
      }
      __syncthreads();
      const int kk = tid >> 3, qb = (tid & 7) * 4;
      #pragma unroll
      for (int p = 0; p < 4; ++p) {
        int q = qb + p * 32;
        float4 v = make_float4(smem[(q + 0) * 36 + kk], smem[(q + 1) * 36 + kk],
                               smem[(q + 2) * 36 + kk], smem[(q + 3) * 36 + kk]);
        int kabs = k0 + kk;
        int row = utt * 128 + (kabs >> 2);
        int col = in_off + (kabs & 3) * 128 + q;
        *(float4*)&P.out[(size_t)row * ROW_ + col] = v;
      }
    }
    multi_barrier(&bar[0], &bar[1], 256);

    // ---- B: 64 recurrent steps ----
    {
      float cst[4] = {0.f, 0.f, 0.f, 0.f};
      float* sH  = smem;              // [16][516]
      float* scr = smem + 16 * 516;   // [128][16]
      for (int t = 0; t < T_; ++t) {
        if (t > 0) multi_barrier(&bar[2 + sg], &bar[18 + sg], 16);
        if (t == 0) {
          for (int i = tid; i < 16 * 128; i += 256) {
            int s = i >> 7, k4 = (i & 127) * 4;
            *(float4*)&sH[s * 516 + k4] = make_float4(0.f, 0.f, 0.f, 0.f);
          }
        } else {
          for (int i = tid; i < 16 * 128; i += 256) {
            int s = i >> 7, k4 = (i & 127) * 4;
            float4 v = *(const float4*)&P.out[((size_t)((sg * 16 + s) * 64 + (t - 1))) * ROW_
                                              + out_off + k4];
            *(float4*)&sH[s * 516 + k4] = v;
          }
        }
        __syncthreads();
        float acc[16];
        #pragma unroll
        for (int i = 0; i < 16; ++i) acc[i] = 0.f;
        {
          const float* wp = P.out + (size_t)(ut * 128 + kh * 64) * ROW_ + in_off + ug * 16;
          const float* hp = sH + sl * 516 + kh * 256;
          for (int kq = 0; kq < 64; ++kq) {
            float4 hv4 = *(const float4*)(hp + kq * 4);
            #pragma unroll
            for (int kk = 0; kk < 4; ++kk) {
              float hv = (&hv4.x)[kk];
              const float* wb = wp + kk * 128;
              float4 w0 = *(const float4*)(wb);
              float4 w1 = *(const float4*)(wb + 4);
              float4 w2 = *(const float4*)(wb + 8);
              float4 w3 = *(const float4*)(wb + 12);
              acc[0]  += w0.x * hv; acc[1]  += w0.y * hv; acc[2]  += w0.z * hv; acc[3]  += w0.w * hv;
              acc[4]  += w1.x * hv; acc[5]  += w1.y * hv; acc[6]  += w1.z * hv; acc[7]  += w1.w * hv;
              acc[8]  += w2.x * hv; acc[9]  += w2.y * hv; acc[10] += w2.z * hv; acc[11] += w2.w * hv;
              acc[12] += w3.x * hv; acc[13] += w3.y * hv; acc[14] += w3.z * hv; acc[15] += w3.w * hv;
            }
            wp += ROW_;
          }
        }
        __syncthreads();
        if (kh == 1) {
          float* s = &scr[(sl * 8 + ug) * 16];
          #pragma unroll
          for (int i = 0; i < 16; ++i) s[i] = acc[i];
        }
        __syncthreads();
        if (kh == 0) {
          const float* s = &scr[(sl * 8 + ug) * 16];
          #pragma unroll
          for (int i = 0; i < 16; ++i) acc[i] += s[i];
          const int b = sg * 16 + sl;
          const size_t mrow = (size_t)(b * 64 + t) * ROW_;
          const int ub = ut * 32 + ug * 4;
          float4 zi4 = *(const float4*)&P.out[mrow + 0 * 512 + ub];
          float4 zf4 = *(const float4*)&P.out[mrow + 1 * 512 + ub];
          float4 zg4 = *(const float4*)&P.out[mrow + 2 * 512 + ub];
          float4 zo4 = *(const float4*)&P.out[mrow + 3 * 512 + ub];
          float hq[4];
          #pragma unroll
          for (int uu = 0; uu < 4; ++uu) {
            float zi = (&zi4.x)[uu] + acc[uu * 4 + 0];
            float zf = (&zf4.x)[uu] + acc[uu * 4 + 1];
            float zg = (&zg4.x)[uu] + acc[uu * 4 + 2];
            float zo = (&zo4.x)[uu] + acc[uu * 4 + 3];
            float cp = (t == 0) ? 0.f : cst[uu];
            float si = 1.f / (1.f + expf(-zi));
            float sf = 1.f / (1.f + expf(-zf));
            float so = 1.f / (1.f + expf(-zo));
            float cn = sf * cp + si * tanhf(zg);
            cst[uu] = cn;
            hq[uu] = so * tanhf(cn);
          }
          *(float4*)&P.out[mrow + out_off + ub] = make_float4(hq[0], hq[1], hq[2], hq[3]);
        }
      }
    }
    multi_barrier(&bar[0], &bar[1], 256);
  }
}

// ---------------- label-routed combine FC (+ length branch, label argmax) ----
__global__ __launch_bounds__(256) void k_combine(Params P) {
  __shared__ float sA[16][CIN_];
  __shared__ float sLen[64];
  int b = blockIdx.x >> 2, t0 = (blockIdx.x & 3) * 16;
  int tid = threadIdx.x;
  int li = P.length[b] - 1;
  if (tid < 64) {
    float v = P.lenW[tid * 64 + li] + P.lenB[tid];
    sLen[tid] = v > 0.f ? v : 0.f;
  }
  float best = P.label[b * 8]; int l = 0;
  #pragma unroll
  for (int k = 1; k < 8; ++k) {
    float lv = P.label[b * 8 + k];
    if (lv > best) { best = lv; l = k; }
  }
  __syncthreads();
  for (int tt = 0; tt < 16; ++tt) {
    int t = t0 + tt;
    for (int k = tid; k < CIN_; k += 256) {
      float v;
      if (k < 640) {
        int a = k >> 7, e = k & 127;
        int xi = P.x[((b * T_ + t) * 5) + a];
        v = P.emb[a][xi * EMB_ + e];
      } else {
        v = sLen[k - 640];
      }
      sA[tt][k] = v;
    }
  }
  __syncthreads();
  int hg = tid & 127, mh = tid >> 7;
  int h = hg * 4, tb = mh * 8;
  const float* W0 = P.combW + ((size_t)(l * HID_ + h)) * CIN_;
  float acc[4][8];
  #pragma unroll
  for (int c = 0; c < 4; ++c)
    #pragma unroll
    for (int m = 0; m < 8; ++m) acc[c][m] = 0.f;
  for (int k = 0; k < CIN_; k += 4) {
    float4 w0 = *(const float4*)(const void*)(W0 + k);
    float4 w1 = *(const float4*)(const void*)(W0 + CIN_ + k);
    float4 w2 = *(const float4*)(const void*)(W0 + 2 * CIN_ + k);
    float4 w3 = *(const float4*)(const void*)(W0 + 3 * CIN_ + k);
    #pragma unroll
    for (int m = 0; m < 8; ++m) {
      float4 av = *(const float4*)&sA[tb + m][k];
      acc[0][m] += w0.x*av.x + w0.y*av.y + w0.z*av.z + w0.w*av.w;
      acc[1][m] += w1.x*av.x + w1.y*av.y + w1.z*av.z + w1.w*av.w;
      acc[2][m] += w2.x*av.x + w2.y*av.y + w2.z*av.z + w2.w*av.w;
      acc[3][m] += w3.x*av.x + w3.y*av.y + w3.z*av.z + w3.w*av.w;
    }
  }
  #pragma unroll
  for (int c = 0; c < 4; ++c) {
    float bias = P.combB[l * HID_ + h + c];
    #pragma unroll
    for (int m = 0; m < 8; ++m) {
      float v = acc[c][m] + bias;
      P.out[((size_t)(b * T_ + t0 + tb + m)) * ROW_ + OFF_HA + h + c] = v > 0.f ? v : 0.f;
    }
  }
}

// ---------------- heads (attr fused) -> logits overwrite own rows ----------
__global__ __launch_bounds__(256) void k_heads(Params P) {
  __shared__ float sN[8][512];
  __shared__ float sH[8][512];
  __shared__ float sAt[8][5][64];
  int m0 = blockIdx.x * 8;
  int tid = threadIdx.x;
  for (int i = tid; i < 8 * 512; i += 256) {
    int tt = i >> 9, k = i & 511;
    int a = k >> 7, e = k & 127;
    int xi = P.xnow[((m0 + tt) * 5) + a];
    sN[tt][k] = P.emb[a][xi * EMB_ + e];
    sH[tt][k] = P.out[((size_t)(m0 + tt)) * ROW_ + OFF_HA + k];
  }
  for (int i = tid; i < 8 * 64; i += 256) {
    int tt = i >> 6, j = i & 63;
    sAt[tt][0][j] = P.pad[j];
  }
  __syncthreads();
  {
    int ih = tid >> 6, j = tid & 63;
    int Klen = (ih + 1) * EMB_;
    const float* Wr = P.condW[ih] + (size_t)j * Klen;
    float acc[8] = {0.f,0.f,0.f,0.f,0.f,0.f,0.f,0.f};
    for (int k = 0; k < Klen; k += 4) {
      float4 w = *(const float4*)(const void*)(Wr + k);
      #pragma unroll
      for (int m = 0; m < 8; ++m) {
        float4 av = *(const float4*)&sN[m][k];
        acc[m] += w.x*av.x + w.y*av.y + w.z*av.z + w.w*av.w;
      }
    }
    float bias = P.condB[ih][j];
    #pragma unroll
    for (int m = 0; m < 8; ++m) {
      float v = acc[m] + bias;
      sAt[m][ih + 1][j] = v > 0.f ? v : 0.f;
    }
  }
  __syncthreads();
  const int V[5] = {256, 256, 1024, 1024, 512};
  int off = 0;
  int cg = tid & 127, mh = tid >> 7, tb = mh * 4;
  for (int head = 0; head < 5; ++head) {
    const float* W = P.outW[head];
    const float* bias = P.outB[head];
    int Vh = V[head];
    for (int c0 = cg * 4; c0 < Vh; c0 += 512) {
      const float* Wr = W + (size_t)c0 * HA_;
      float acc[4][4];
      #pragma unroll
      for (int c = 0; c < 4; ++c)
        #pragma unroll
        for (int m = 0; m < 4; ++m) acc[c][m] = 0.f;
      for (int k = 0; k < 512; k += 4) {
        float4 w0 = *(const float4*)(const void*)(Wr + k);
        float4 w1 = *(const float4*)(const void*)(Wr + HA_ + k);
        float4 w2 = *(const float4*)(const void*)(Wr + 2 * HA_ + k);
        float4 w3 = *(const float4*)(const void*)(Wr + 3 * HA_ + k);
        #pragma unroll
        for (int m = 0; m < 4; ++m) {
          float4 av = *(const float4*)&sH[tb + m][k];
          acc[0][m] += w0.x*av.x + w0.y*av.y + w0.z*av.z + w0.w*av.w;
          acc[1][m] += w1.x*av.x + w1.y*av.y + w1.z*av.z + w1.w*av.w;
          acc[2][m] += w2.x*av.x + w2.y*av.y + w2.z*av.z + w2.w*av.w;
          acc[3][m] += w3.x*av.x + w3.y*av.y + w3.z*av.z + w3.w*av.w;
        }
      }
      for (int k = 0; k < 64; k += 4) {
        float4 w0 = *(const float4*)(const void*)(Wr + 512 + k);
        float4 w1 = *(const float4*)(const void*)(Wr + HA_ + 512 + k);
        float4 w2 = *(const float4*)(const void*)(Wr + 2 * HA_ + 512 + k);
        float4 w3 = *(const float4*)(const void*)(Wr + 3 * HA_ + 512 + k);
        #pragma unroll
        for (int m = 0; m < 4; ++m) {
          float4 av = *(const float4*)&sAt[tb + m][head][k];
          acc[0][m] += w0.x*av.x + w0.y*av.y + w0.z*av.z + w0.w*av.w;
          acc[1][m] += w1.x*av.x + w1.y*av.y + w1.z*av.z + w1.w*av.w;
          acc[2][m] += w2.x*av.x + w2.y*av.y + w2.z*av.z + w2.w*av.w;
          acc[3][m] += w3.x*av.x + w3.y*av.y + w3.z*av.z + w3.w*av.w;
        }
      }
      #pragma unroll
      for (int c = 0; c < 4; ++c) {
        float bi = bias[c0 + c];
        #pragma unroll
        for (int m = 0; m < 4; ++m)
          P.out[((size_t)(m0 + tb + m)) * ROW_ + off + c0 + c] = acc[c][m] + bi;
      }
    }
    off += Vh;
  }
}

// ---------------- in-place log_softmax over each head's slice ----------------
__global__ __launch_bounds__(256) void k_lsm(Params P) {
  __shared__ float sred[4];
  int m = blockIdx.x;
  float* row0 = P.out + (size_t)m * ROW_;
  int tid = threadIdx.x, lane = tid & 63, wid = tid >> 6;
  const int V[5] = {256, 256, 1024, 1024, 512};
  int off = 0;
  for (int head = 0; head < 5; ++head) {
    float* row = row0 + off; int Vh = V[head];
    float mx = -1e30f;
    for (int c = tid; c < Vh; c += 256) mx = fmaxf(mx, row[c]);
    for (int o = 32; o > 0; o >>= 1) mx = fmaxf(mx, __shfl_down(mx, o, 64));
    if (lane == 0) sred[wid] = mx;
    __syncthreads();
    mx = fmaxf(fmaxf(sred[0], sred[1]), fmaxf(sred[2], sred[3]));
    __syncthreads();
    float s = 0.f;
    for (int c = tid; c < Vh; c += 256) s += expf(row[c] - mx);
    for (int o = 32; o > 0; o >>= 1) s += __shfl_down(s, o, 64);
    if (lane == 0) sred[wid] = s;
    __syncthreads();
    float lse = mx + logf(sred[0] + sred[1] + sred[2] + sred[3]);
    __syncthreads();
    for (int c = tid; c < Vh; c += 256) row[c] = row[c] - lse;
    off += Vh;
  }
}

extern "C" void kernel_launch(void* const* d_in, const int* in_sizes, int n_in,
                              void* d_out, int out_size, void* d_ws, size_t ws_size,
                              hipStream_t stream) {
  (void)in_sizes; (void)n_in; (void)out_size; (void)ws_size;
  Params P;
  P.label  = (const float*)d_in[0];
  P.length = (const int*)  d_in[1];
  P.x      = (const int*)  d_in[2];
  P.xnow   = (const int*)  d_in[3];
  for (int i = 0; i < 5; ++i) P.emb[i] = (const float*)d_in[4 + i];
  P.pad = (const float*)d_in[9];
  for (int i = 0; i < 4; ++i) {
    P.condW[i] = (const float*)d_in[10 + 2 * i];
    P.condB[i] = (const float*)d_in[11 + 2 * i];
  }
  P.lenW  = (const float*)d_in[18]; P.lenB  = (const float*)d_in[19];
  P.combW = (const float*)d_in[20]; P.combB = (const float*)d_in[21];
  P.Wih   = (const float*)d_in[22]; P.Whh   = (const float*)d_in[23];
  P.bih   = (const float*)d_in[24]; P.bhh   = (const float*)d_in[25];
  for (int i = 0; i < 5; ++i) {
    P.outW[i] = (const float*)d_in[26 + 2 * i];
    P.outB[i] = (const float*)d_in[27 + 2 * i];
  }
  P.bar = (unsigned int*)d_ws;
  P.out = (float*)d_out;

  hipMemsetAsync(d_ws, 0, 256, stream);
  k_combine<<<1024, 256, 0, stream>>>(P);
  void* args[] = { &P };
  hipLaunchCooperativeKernel((void*)k_lstm, dim3(256), dim3(256), args, 0, stream);
  k_heads<<<2048,  256, 0, stream>>>(P);
  k_lsm  <<<16384, 256, 0, stream>>>(P);
}